// Round 1
// baseline (155.461 us; speedup 1.0000x reference)
//
#include <hip/hip_runtime.h>

#define HH   128
#define WW   128
#define CC   64
#define BB   4
#define TILE 8
#define HALO 12   // TILE + 2*2
#define CPAD 68   // 64 + 4: breaks stride-64 bank degeneracy, keeps 16B align

// ---------------------------------------------------------------------------
// Kernel A: q = wy*y + by, v = wx*x + bx, stored channel-last (b,h,w,c) in ws.
// One block = 64 consecutive pixels of one (b,h) row. 256 threads.
// ---------------------------------------------------------------------------
__global__ __launch_bounds__(256, 2)
void qv_kernel(const float* __restrict__ x, const float* __restrict__ y,
               const float* __restrict__ wx, const float* __restrict__ bx,
               const float* __restrict__ wy, const float* __restrict__ by,
               float* __restrict__ qws, float* __restrict__ vws)
{
    __shared__ __align__(16) float yls[CC][64];
    __shared__ __align__(16) float xls[CC][64];
    __shared__ __align__(16) float wyT[CC][CPAD];  // wyT[ic][oc]
    __shared__ __align__(16) float wxT[CC][CPAD];

    const int t  = threadIdx.x;
    const int b  = blockIdx.z;
    const int h  = blockIdx.y;
    const int w0 = blockIdx.x * 64;

    // ---- stage inputs (coalesced: lanes stride-1 in w) ----
    {
        const int wl  = t & 63;
        const int icb = t >> 6;                      // 0..3
        const long base = (((long)b * CC) * HH + h) * WW + w0 + wl;
        #pragma unroll
        for (int i = 0; i < 16; ++i) {
            const int ic = icb + i * 4;
            yls[ic][wl] = y[base + (long)ic * HH * WW];
            xls[ic][wl] = x[base + (long)ic * HH * WW];
        }
        // transposed weights: read coalesced (ic stride-1), write LDS
        const int ic2 = t & 63;
        const int ocb = t >> 6;                      // 0..3
        #pragma unroll
        for (int i = 0; i < 16; ++i) {
            const int oc = ocb + i * 4;
            wyT[ic2][oc] = wy[oc * 64 + ic2];
            wxT[ic2][oc] = wx[oc * 64 + ic2];
        }
    }
    __syncthreads();

    // ---- 4 oc x 4 w register-blocked matvec ----
    const int oc0 = (t & 15) * 4;
    const int wb  = (t >> 4) * 4;

    float aq[4][4] = {{0.f}}, av[4][4] = {{0.f}};
    #pragma unroll 8
    for (int ic = 0; ic < CC; ++ic) {
        const float4 wy4 = *(const float4*)&wyT[ic][oc0];
        const float4 wx4 = *(const float4*)&wxT[ic][oc0];
        const float4 y4  = *(const float4*)&yls[ic][wb];
        const float4 x4  = *(const float4*)&xls[ic][wb];
        const float wyf[4] = {wy4.x, wy4.y, wy4.z, wy4.w};
        const float wxf[4] = {wx4.x, wx4.y, wx4.z, wx4.w};
        const float yf[4]  = {y4.x, y4.y, y4.z, y4.w};
        const float xf[4]  = {x4.x, x4.y, x4.z, x4.w};
        #pragma unroll
        for (int i = 0; i < 4; ++i)
            #pragma unroll
            for (int j = 0; j < 4; ++j) {
                aq[i][j] += wyf[i] * yf[j];
                av[i][j] += wxf[i] * xf[j];
            }
    }

    // ---- bias + store channel-last ----
    const float4 by4 = *(const float4*)&by[oc0];
    const float4 bx4 = *(const float4*)&bx[oc0];
    const float byf[4] = {by4.x, by4.y, by4.z, by4.w};
    const float bxf[4] = {bx4.x, bx4.y, bx4.z, bx4.w};
    const long ob = (((long)b * HH + h) * WW + w0) * 64;
    #pragma unroll
    for (int j = 0; j < 4; ++j) {
        float4 qo, vo;
        qo.x = aq[0][j] + byf[0]; qo.y = aq[1][j] + byf[1];
        qo.z = aq[2][j] + byf[2]; qo.w = aq[3][j] + byf[3];
        vo.x = av[0][j] + bxf[0]; vo.y = av[1][j] + bxf[1];
        vo.z = av[2][j] + bxf[2]; vo.w = av[3][j] + bxf[3];
        const long a = ob + (long)(wb + j) * 64 + oc0;
        *(float4*)&qws[a] = qo;
        *(float4*)&vws[a] = vo;
    }
}

// ---------------------------------------------------------------------------
// Kernel B: per 8x8 pixel tile — scores (25-neighbor q·q_n), softmax,
// v-aggregate, final 1x1 conv (wo,bo) + residual x.  256 threads.
// ---------------------------------------------------------------------------
__global__ __launch_bounds__(256, 2)
void attn_kernel(const float* __restrict__ qws, const float* __restrict__ vws,
                 const float* __restrict__ x, const float* __restrict__ wo,
                 const float* __restrict__ bo, float* __restrict__ out)
{
    __shared__ __align__(16) float qh[HALO * HALO][CPAD];  // 39168 B (agg reuses)
    __shared__ __align__(16) float vh[HALO * HALO][CPAD];  // 39168 B

    const int t   = threadIdx.x;
    const int b   = blockIdx.z;
    const int ty0 = blockIdx.y * TILE;
    const int tx0 = blockIdx.x * TILE;

    // ---- stage q/v halo (zero-filled OOB == zero-padded unfold of conv out) ----
    for (int i = t; i < HALO * HALO * 16; i += 256) {
        const int pix = i >> 4;
        const int c4  = (i & 15) * 4;
        const int hy  = pix / HALO, hx = pix % HALO;
        const int gy  = ty0 + hy - 2, gx = tx0 + hx - 2;
        float4 q4 = {0.f, 0.f, 0.f, 0.f}, v4 = {0.f, 0.f, 0.f, 0.f};
        if (gy >= 0 && gy < HH && gx >= 0 && gx < WW) {
            const long a = ((((long)b * HH + gy) * WW + gx) << 6) + c4;
            q4 = *(const float4*)&qws[a];
            v4 = *(const float4*)&vws[a];
        }
        *(float4*)&qh[pix][c4] = q4;
        *(float4*)&vh[pix][c4] = v4;
    }
    __syncthreads();

    // ---- scores: 4 lanes per pixel, 16 channels each ----
    const int p   = t >> 2;          // pixel 0..63
    const int sub = t & 3;           // channel quarter
    const int py  = p >> 3, px = p & 7;
    const int cpix = (py + 2) * HALO + (px + 2);
    const int c0   = sub * 16;

    float4 qc[4];
    #pragma unroll
    for (int j = 0; j < 4; ++j) qc[j] = *(const float4*)&qh[cpix][c0 + 4 * j];

    float sc[25];
    #pragma unroll
    for (int dy = 0; dy < 5; ++dy)
        #pragma unroll
        for (int dx = 0; dx < 5; ++dx) {
            const float* qn = &qh[(py + dy) * HALO + (px + dx)][c0];
            float s = 0.f;
            #pragma unroll
            for (int j = 0; j < 4; ++j) {
                const float4 q4 = *(const float4*)&qn[4 * j];
                s += qc[j].x * q4.x + qc[j].y * q4.y
                   + qc[j].z * q4.z + qc[j].w * q4.w;
            }
            s += __shfl_xor(s, 1);   // sum the 4 channel-quarters
            s += __shfl_xor(s, 2);   // (bit-identical result on all 4 lanes)
            sc[dy * 5 + dx] = s;
        }

    // ---- softmax over 25 (redundant per lane, consistent) ----
    float mx = sc[0];
    #pragma unroll
    for (int k = 1; k < 25; ++k) mx = fmaxf(mx, sc[k]);
    float sum = 0.f;
    #pragma unroll
    for (int k = 0; k < 25; ++k) { sc[k] = __expf(sc[k] - mx); sum += sc[k]; }
    const float inv = 1.f / sum;

    // ---- aggregate v ----
    float4 agg[4] = {{0.f,0.f,0.f,0.f},{0.f,0.f,0.f,0.f},
                     {0.f,0.f,0.f,0.f},{0.f,0.f,0.f,0.f}};
    #pragma unroll
    for (int dy = 0; dy < 5; ++dy)
        #pragma unroll
        for (int dx = 0; dx < 5; ++dx) {
            const float a = sc[dy * 5 + dx] * inv;
            const float* vn = &vh[(py + dy) * HALO + (px + dx)][c0];
            #pragma unroll
            for (int j = 0; j < 4; ++j) {
                const float4 v4 = *(const float4*)&vn[4 * j];
                agg[j].x += a * v4.x; agg[j].y += a * v4.y;
                agg[j].z += a * v4.z; agg[j].w += a * v4.w;
            }
        }

    __syncthreads();                       // all q reads complete
    float* aggL = &qh[0][0];               // reuse q region: agg[64 pix][CPAD]
    #pragma unroll
    for (int j = 0; j < 4; ++j)
        *(float4*)&aggL[p * CPAD + c0 + 4 * j] = agg[j];
    __syncthreads();

    // ---- final 1x1 conv + residual; remap: lane = pixel, wave = oc-block ----
    const int pp  = t & 63;
    const int ob2 = t >> 6;                // oc block of 16 (wave-uniform)
    float acc[16];
    #pragma unroll
    for (int o = 0; o < 16; ++o) acc[o] = bo[ob2 * 16 + o];
    #pragma unroll
    for (int c4 = 0; c4 < 16; ++c4) {
        const float4 a4 = *(const float4*)&aggL[pp * CPAD + c4 * 4];
        #pragma unroll
        for (int o = 0; o < 16; ++o) {
            const float4 w4 = *(const float4*)&wo[(ob2 * 16 + o) * 64 + c4 * 4];
            acc[o] += a4.x * w4.x + a4.y * w4.y + a4.z * w4.z + a4.w * w4.w;
        }
    }
    const int gh = ty0 + (pp >> 3), gw = tx0 + (pp & 7);
    #pragma unroll
    for (int o = 0; o < 16; ++o) {
        const int oc = ob2 * 16 + o;
        const long a = (((long)(b * CC + oc)) * HH + gh) * WW + gw;
        out[a] = acc[o] + x[a];
    }
}

// ---------------------------------------------------------------------------
extern "C" void kernel_launch(void* const* d_in, const int* in_sizes, int n_in,
                              void* d_out, int out_size, void* d_ws, size_t ws_size,
                              hipStream_t stream) {
    const float* x  = (const float*)d_in[0];
    const float* y  = (const float*)d_in[1];
    const float* wx = (const float*)d_in[2];
    const float* bx = (const float*)d_in[3];
    const float* wy = (const float*)d_in[4];
    const float* by = (const float*)d_in[5];
    const float* wo = (const float*)d_in[6];
    const float* bo = (const float*)d_in[7];
    float* out = (float*)d_out;

    float* qws = (float*)d_ws;                              // 16 MB
    float* vws = qws + (size_t)BB * CC * HH * WW;           // +16 MB

    dim3 gA(WW / 64, HH, BB);       // 2 x 128 x 4 = 1024 blocks
    qv_kernel<<<gA, 256, 0, stream>>>(x, y, wx, bx, wy, by, qws, vws);

    dim3 gB(WW / TILE, HH / TILE, BB);  // 16 x 16 x 4 = 1024 blocks
    attn_kernel<<<gB, 256, 0, stream>>>(qws, vws, x, wo, bo, out);
}